// Round 3
// baseline (187.221 us; speedup 1.0000x reference)
//
#include <hip/hip_runtime.h>
#include <hip/hip_bf16.h>

#define BATCH 4096

typedef unsigned short u16;
typedef _Float16 half2v __attribute__((ext_vector_type(2)));
typedef _Float16 half4 __attribute__((ext_vector_type(4)));
typedef _Float16 half8 __attribute__((ext_vector_type(8)));
typedef short bs8 __attribute__((ext_vector_type(8)));
typedef u16 u16x4 __attribute__((ext_vector_type(4)));
typedef float floatx4 __attribute__((ext_vector_type(4)));
typedef float floatx16 __attribute__((ext_vector_type(16)));

__device__ inline u16 f2bf_hw(float f) {        // HW cvt (RNE)
    __hip_bfloat16 b = __float2bfloat16(f);
    return *(u16*)&b;
}

// ---------------------------------------------------------------------------
// Prep (466 blocks exact): w1h gabor f16 [32][16] (K 9->16 zero-pad);
// w2h f16 [tap][oc][k] ic-interleaved (k=2c+p <-> channel c+16p);
// wbf bf16 [128][3136] = straight vectorized cast of fc1_w.
// ---------------------------------------------------------------------------
__global__ __launch_bounds__(256) void prep_kernel(
        const float* __restrict__ theta, const float* __restrict__ sigma,
        const float* __restrict__ gamma, const float* __restrict__ lambd,
        const float* __restrict__ psi, const float* __restrict__ conv2_w,
        const float* __restrict__ fc1_w, _Float16* __restrict__ w1h,
        _Float16* __restrict__ w2h, u16* __restrict__ wbf) {
    int id = blockIdx.x * 256 + threadIdx.x;
    if (id < 512) {
        int g = id >> 4, t = id & 15;
        float v = 0.0f;
        if (t < 9) {
            int i = t / 3, j = t % 3;
            float xg = (float)i - 1.0f;      // meshgrid 'ij'
            float yg = (float)j - 1.0f;
            if (g < 16) {
                float th = theta[g];
                float c = cosf(th), s = sinf(th);
                float xt = xg * c + yg * s;
                float yt = -xg * s + yg * c;
                float sx = sigma[g];
                float sy = sx / gamma[g];
                float env = expf(-0.5f *
                                 (xt * xt / (sx * sx) + yt * yt / (sy * sy)));
                float car =
                    cosf(6.28318530717958647692f * xt / lambd[g] + psi[g]);
                v = env * car;
            } else {
                v = (t == 4) ? 1.0f : 0.0f;
            }
        }
        w1h[id] = (_Float16)v;
    } else if (id < 512 + 18432) {
        int t2 = id - 512;
        int tap = t2 / 2048, rem = t2 % 2048;
        int oc = rem / 32, k = rem % 32;
        int ic = (k >> 1) + 16 * (k & 1);     // interleaved channel order
        w2h[t2] = (_Float16)conv2_w[(oc * 32 + ic) * 9 + tap];
    } else {
        int i4 = id - 18944;                  // < 100352 (grid exact)
        float4 v = ((const float4*)fc1_w)[i4];
        u16x4 o;
        o[0] = f2bf_hw(v.x);
        o[1] = f2bf_hw(v.y);
        o[2] = f2bf_hw(v.z);
        o[3] = f2bf_hw(v.w);
        ((u16x4*)wbf)[i4] = o;
    }
}

// ---------------------------------------------------------------------------
// Fused conv, ONE image per 256-thread block (4 waves).
// VALU-diet round: (a) img fill via shift/mask (no int div), single phase,
// border handled by select; (b) a1s zeroed only on the 60-position border
// ring (the only zeros conv2 ever reads); (c) conv1 A-gather 2-deep
// software-pipelined (prefetch next tile's 4 u16s before current MFMA) to
// hide the ~120cy LDS scalar-read latency.
// img16 stride 36 halfs: conv1 gather conflict-free.
// ---------------------------------------------------------------------------
__global__ __launch_bounds__(256) void fused_conv_kernel(
        const float* __restrict__ x, const _Float16* __restrict__ w1h,
        const _Float16* __restrict__ w2h, const float* __restrict__ conv2_b,
        u16* __restrict__ a2) {
    __shared__ _Float16 img16[30][36];
    __shared__ __align__(16) _Float16 a1s[16][16][40];
    __shared__ __align__(16) u16 out2[64 * 49];

    int t = threadIdx.x;
    int n = blockIdx.x;
    int lane = t & 63;
    int w = t >> 6;                    // wave 0..3
    int l16 = lane & 15;
    int quad = lane >> 4;
    int l32 = lane & 31;
    int h = lane >> 5;

    // ---- conv2 B-fragment preload (global/L2), latency hidden by conv1 ----
    int nt = w & 1;
    int mt0 = w >> 1;
    int oc = nt * 32 + l32;
    half8 bE[9], bO[9];
    const _Float16* bp = w2h + (size_t)oc * 32 + h * 8;
#pragma unroll
    for (int tt = 0; tt < 9; ++tt) {
        bE[tt] = *(const half8*)(bp + tt * 2048);
        bO[tt] = *(const half8*)(bp + tt * 2048 + 16);
    }
    float bias = conv2_b[oc];

    // ---- phase 1 (single barrier): a1s ring-zero + img16 fill ----
    // a1s border ring (rows 0,15 all cols; cols 0,15 rows 1..14), k 0..31:
    // 60 positions x 4 int4.
    for (int i = t; i < 240; i += 256) {
        int pos = i >> 2, ch = i & 3;
        int r, c;
        if (pos < 16)      { r = 0;        c = pos; }
        else if (pos < 32) { r = 15;       c = pos - 16; }
        else if (pos < 46) { r = pos - 31; c = 0; }
        else               { r = pos - 45; c = 15; }
        *(int4*)&a1s[r][c][ch * 8] = int4{0, 0, 0, 0};
    }
    // img16: rows 0..29, cols 0..31 (cols 32..35 never read); interior
    // (1..28)^2 from x, border zero — shift/mask indexing, no divides.
    const float* xim = x + (size_t)n * 784;
    for (int i = t; i < 960; i += 256) {
        int r = i >> 5, c = i & 31;
        bool inter = (r >= 1) & (r <= 28) & (c >= 1) & (c <= 28);
        float v = inter ? xim[(r - 1) * 28 + (c - 1)] : 0.0f;
        img16[r][c] = (_Float16)v;
    }
    __syncthreads();

    // ---- conv1 MFMA: M pool-major, N=32, K=16 (taps >=9 clamped; B rows
    //      zero there so garbage A values contribute nothing) ----
    half4 b1a = *(const half4*)&w1h[l16 * 16 + quad * 4];
    half4 b1b = *(const half4*)&w1h[(16 + l16) * 16 + quad * 4];
    int t0 = quad * 4;
    int u0 = t0 < 9 ? t0 : 8, u1 = t0 + 1 < 9 ? t0 + 1 : 8;
    int u2 = t0 + 2 < 9 ? t0 + 2 : 8, u3 = t0 + 3 < 9 ? t0 + 3 : 8;
    int off0 = (u0 / 3) * 36 + (u0 % 3);
    int off1 = (u1 / 3) * 36 + (u1 % 3);
    int off2 = (u2 / 3) * 36 + (u2 % 3);
    int off3 = (u3 / 3) * 36 + (u3 % 3);
    int sy = (l16 & 3) >> 1, sx = l16 & 1;

    int pool0 = w * 4 + (l16 >> 2);
    int a14 = pool0 >= 14 ? 1 : 0;
    int b14 = pool0 - 14 * a14;
    int pl0 = w * 4 + quad;
    int pa = pl0 >= 14 ? 1 : 0;
    int pb = pl0 - 14 * pa;

    // prime the 2-deep pipeline
    const _Float16* p0 = &img16[2 * a14 + sy][2 * b14 + sx];
    half4 avc;
    avc[0] = p0[off0];
    avc[1] = p0[off1];
    avc[2] = p0[off2];
    avc[3] = p0[off3];

    for (int mt = w; mt < 49; mt += 4) {
        // advance gather coords, prefetch next tile's fragment
        a14 += 1; b14 += 2;
        if (b14 >= 14) { b14 -= 14; a14 += 1; }
        half4 avn;
        if (mt + 4 < 49) {
            const _Float16* p = &img16[2 * a14 + sy][2 * b14 + sx];
            avn[0] = p[off0];
            avn[1] = p[off1];
            avn[2] = p[off2];
            avn[3] = p[off3];
        }
        floatx4 c0 = {0.f, 0.f, 0.f, 0.f};
        floatx4 c1 = {0.f, 0.f, 0.f, 0.f};
        c0 = __builtin_amdgcn_mfma_f32_16x16x16f16(avc, b1a, c0, 0, 0, 0);
        c1 = __builtin_amdgcn_mfma_f32_16x16x16f16(avc, b1b, c1, 0, 0, 0);
        float m0 = fmaxf(fmaxf(c0[0], c0[1]), fmaxf(c0[2], c0[3]));
        float m1 = fmaxf(fmaxf(c1[0], c1[1]), fmaxf(c1[2], c1[3]));
        half2v pk;
        pk[0] = (_Float16)fmaxf(m0, 0.0f);    // channel l16    -> k=2*l16
        pk[1] = (_Float16)fmaxf(m1, 0.0f);    // channel l16+16 -> k=2*l16+1
        *(half2v*)&a1s[1 + pa][1 + pb][2 * l16] = pk;
        pa += 1; pb += 2;
        if (pb >= 14) { pb -= 14; pa += 1; }
        avc = avn;
    }
    __syncthreads();

    // ---- conv2 MFMA 32x32x16: nt fixed/wave, mts strided by 2; single
    //      accumulator chain ----
    for (int mt = mt0; mt < 7; mt += 2) {
        int pool = mt * 8 + (l32 >> 2);
        int sub = l32 & 3;
        int pc = pool < 49 ? pool : 48;
        int y = 2 * (pc / 7) + (sub >> 1);
        int xq = 2 * (pc % 7) + (sub & 1);
        const _Float16* ap = &a1s[y][xq][h * 8];
        floatx16 acc = {};
#pragma unroll
        for (int tt = 0; tt < 9; ++tt) {
            int ao = ((tt / 3) * 16 + (tt % 3)) * 40;
            half8 avE = *(const half8*)(ap + ao);
            half8 avO = *(const half8*)(ap + ao + 16);
            acc = __builtin_amdgcn_mfma_f32_32x32x16_f16(avE, bE[tt], acc,
                                                         0, 0, 0);
            acc = __builtin_amdgcn_mfma_f32_32x32x16_f16(avO, bO[tt], acc,
                                                         0, 0, 0);
        }
#pragma unroll
        for (int rg = 0; rg < 4; ++rg) {
            int pl = mt * 8 + 2 * rg + h;
            if (pl < 49) {
                float v0 = acc[rg * 4 + 0];
                float v1 = acc[rg * 4 + 1];
                float v2 = acc[rg * 4 + 2];
                float v3 = acc[rg * 4 + 3];
                float mx = fmaxf(fmaxf(v0, v1), fmaxf(v2, v3));
                out2[oc * 49 + pl] = f2bf_hw(fmaxf(mx + bias, 0.0f));
            }
        }
    }
    __syncthreads();

    // ---- contiguous copy LDS -> a2 (3136 halfs = 784 uint2) ----
    uint2* dst = (uint2*)(a2 + (size_t)n * 3136);
    const uint2* src = (const uint2*)&out2[0];
    for (int i = t; i < 784; i += 256) dst[i] = src[i];
}

// ---------------------------------------------------------------------------
// fc1 + fc2, M-split: 512 blocks x 8 images (rows duplicated into the
// 16-row MFMA tile; dup results discarded). Hs[8][8][132] = 33.8 KB ->
// 2 blocks/CU = 32 waves/CU (was 256 blocks = 1/CU = 50% cap).
// 16 waves = 8 strided K-eighths x 2 N-halves, 4 acc chains.
// ---------------------------------------------------------------------------
__global__ __launch_bounds__(1024) void fc_kernel(
        const u16* __restrict__ A, const u16* __restrict__ Wbf,
        const float* __restrict__ fc1_b, const float* __restrict__ fc2_w,
        const float* __restrict__ fc2_b, float* __restrict__ out) {
    __shared__ float Hs[8][8][132];
    int tid = threadIdx.x;
    int lane = tid & 63;
    int w = tid >> 6;                  // 0..15
    int l16 = lane & 15;
    int quad = lane >> 4;
    int kq = w >> 1;                   // 0..7, strided K-eighth
    int nh = w & 1;                    // N-half
    int m0 = blockIdx.x * 8;

    const u16* aptr = A + (size_t)(m0 + (l16 & 7)) * 3136 + quad * 8;
    const u16* b0 = Wbf + (size_t)(nh * 64 + l16) * 3136 + quad * 8;
    const u16* b1 = b0 + 16 * 3136;
    const u16* b2 = b0 + 32 * 3136;
    const u16* b3 = b0 + 48 * 3136;

    floatx4 ac0 = {0.f, 0.f, 0.f, 0.f};
    floatx4 ac1 = {0.f, 0.f, 0.f, 0.f};
    floatx4 ac2 = {0.f, 0.f, 0.f, 0.f};
    floatx4 ac3 = {0.f, 0.f, 0.f, 0.f};
#pragma unroll 4
    for (int s = kq; s < 98; s += 8) {
        int k0 = s * 32;
        bs8 av = *(const bs8*)(aptr + k0);
        bs8 bv0 = *(const bs8*)(b0 + k0);
        bs8 bv1 = *(const bs8*)(b1 + k0);
        bs8 bv2 = *(const bs8*)(b2 + k0);
        bs8 bv3 = *(const bs8*)(b3 + k0);
        ac0 = __builtin_amdgcn_mfma_f32_16x16x32_bf16(av, bv0, ac0, 0, 0, 0);
        ac1 = __builtin_amdgcn_mfma_f32_16x16x32_bf16(av, bv1, ac1, 0, 0, 0);
        ac2 = __builtin_amdgcn_mfma_f32_16x16x32_bf16(av, bv2, ac2, 0, 0, 0);
        ac3 = __builtin_amdgcn_mfma_f32_16x16x32_bf16(av, bv3, ac3, 0, 0, 0);
    }
    int nb = nh * 64 + l16;
    if (quad < 2) {                    // rows 0..7 real, 8..15 dup
#pragma unroll
        for (int r = 0; r < 4; ++r) {
            int mr = quad * 4 + r;
            Hs[kq][mr][nb] = ac0[r];
            Hs[kq][mr][nb + 16] = ac1[r];
            Hs[kq][mr][nb + 32] = ac2[r];
            Hs[kq][mr][nb + 48] = ac3[r];
        }
    }
    __syncthreads();

    for (int i = tid; i < 1024; i += 1024) {
        int m = i >> 7, k = i & 127;
        float s = Hs[0][m][k] + Hs[1][m][k] + Hs[2][m][k] + Hs[3][m][k] +
                  Hs[4][m][k] + Hs[5][m][k] + Hs[6][m][k] + Hs[7][m][k];
        Hs[0][m][k] = s;
    }
    __syncthreads();

    if (tid < 80) {
        int m = tid / 10, j = tid % 10;
        const float* wr = fc2_w + j * 128;
        float acc = fc2_b[j];
#pragma unroll 16
        for (int k = 0; k < 128; ++k)
            acc += fmaxf(Hs[0][m][k] + fc1_b[k], 0.0f) * wr[k];
        out[(size_t)(m0 + m) * 10 + j] = acc;
    }
}

extern "C" void kernel_launch(void* const* d_in, const int* in_sizes, int n_in,
                              void* d_out, int out_size, void* d_ws,
                              size_t ws_size, hipStream_t stream) {
    const float* x       = (const float*)d_in[0];
    const float* theta   = (const float*)d_in[1];
    const float* sigma   = (const float*)d_in[2];
    const float* gamma   = (const float*)d_in[3];
    const float* lambd   = (const float*)d_in[4];
    const float* psi     = (const float*)d_in[5];
    const float* conv2_w = (const float*)d_in[6];
    const float* conv2_b = (const float*)d_in[7];
    const float* fc1_w   = (const float*)d_in[8];
    const float* fc1_b   = (const float*)d_in[9];
    const float* fc2_w   = (const float*)d_in[10];
    const float* fc2_b   = (const float*)d_in[11];
    float* out = (float*)d_out;

    // ws (26.53 MB, under the 27.07 proven-safe watermark):
    //   a2  bf16 [4096][3136]  : 0          (25,690,112 B)
    //   w1h f16 [32][16]       : 25,690,112 (1,024 B)
    //   w2h f16 [9][64][32]    : 25,691,136 (36,864 B)
    //   wbf bf16 [128][3136]   : 25,728,000 (802,816 B)
    char* ws = (char*)d_ws;
    u16* a2 = (u16*)ws;
    _Float16* w1h = (_Float16*)(ws + 25690112ull);
    _Float16* w2h = (_Float16*)(ws + 25691136ull);
    u16* wbf = (u16*)(ws + 25728000ull);

    prep_kernel<<<466, 256, 0, stream>>>(theta, sigma, gamma, lambd, psi,
                                         conv2_w, fc1_w, w1h, w2h, wbf);
    fused_conv_kernel<<<BATCH, 256, 0, stream>>>(x, w1h, w2h, conv2_b, a2);
    fc_kernel<<<BATCH / 8, 1024, 0, stream>>>(a2, wbf, fc1_b, fc2_w, fc2_b,
                                              out);
}

// Round 5
// 149.526 us; speedup vs baseline: 1.2521x; 1.2521x over previous
//
#include <hip/hip_runtime.h>
#include <hip/hip_bf16.h>

#define BATCH 4096

typedef unsigned short u16;
typedef _Float16 half2v __attribute__((ext_vector_type(2)));
typedef _Float16 half4 __attribute__((ext_vector_type(4)));
typedef _Float16 half8 __attribute__((ext_vector_type(8)));
typedef short bs8 __attribute__((ext_vector_type(8)));
typedef u16 u16x4 __attribute__((ext_vector_type(4)));
typedef float floatx4 __attribute__((ext_vector_type(4)));
typedef float floatx16 __attribute__((ext_vector_type(16)));

__device__ inline u16 f2bf_hw(float f) {        // HW cvt (RNE)
    __hip_bfloat16 b = __float2bfloat16(f);
    return *(u16*)&b;
}

// ---------------------------------------------------------------------------
// Prep (466 blocks exact): w1h gabor f16 [32][16] (K 9->16 zero-pad);
// w2h f16 [tap][oc][k] ic-interleaved (k=2c+p <-> channel c+16p);
// wbf bf16 K-TILED [98][128][32]: tile s holds k=32s..32s+31 for all 128
// rows, so fc's B-loads are wave-contiguous (16 rows x 64B = 1KB/load).
// ---------------------------------------------------------------------------
__global__ __launch_bounds__(256) void prep_kernel(
        const float* __restrict__ theta, const float* __restrict__ sigma,
        const float* __restrict__ gamma, const float* __restrict__ lambd,
        const float* __restrict__ psi, const float* __restrict__ conv2_w,
        const float* __restrict__ fc1_w, _Float16* __restrict__ w1h,
        _Float16* __restrict__ w2h, u16* __restrict__ wbf) {
    int id = blockIdx.x * 256 + threadIdx.x;
    if (id < 512) {
        int g = id >> 4, t = id & 15;
        float v = 0.0f;
        if (t < 9) {
            int i = t / 3, j = t % 3;
            float xg = (float)i - 1.0f;      // meshgrid 'ij'
            float yg = (float)j - 1.0f;
            if (g < 16) {
                float th = theta[g];
                float c = cosf(th), s = sinf(th);
                float xt = xg * c + yg * s;
                float yt = -xg * s + yg * c;
                float sx = sigma[g];
                float sy = sx / gamma[g];
                float env = expf(-0.5f *
                                 (xt * xt / (sx * sx) + yt * yt / (sy * sy)));
                float car =
                    cosf(6.28318530717958647692f * xt / lambd[g] + psi[g]);
                v = env * car;
            } else {
                v = (t == 4) ? 1.0f : 0.0f;
            }
        }
        w1h[id] = (_Float16)v;
    } else if (id < 512 + 18432) {
        int t2 = id - 512;
        int tap = t2 / 2048, rem = t2 % 2048;
        int oc = rem / 32, k = rem % 32;
        int ic = (k >> 1) + 16 * (k & 1);     // interleaved channel order
        w2h[t2] = (_Float16)conv2_w[(oc * 32 + ic) * 9 + tap];
    } else {
        // K-tiled wbf: out u16x4 index i4 -> tile s = i4/1024, q = i4%1024,
        // row = q/8, kin4 = q%8.  dst = wbf[s*4096 + row*32 + kin4*4 ..]
        // src float4 = fc1_w[row*784 + s*8 + kin4] (contiguous float4).
        int i4 = id - 18944;                  // < 100352 (grid exact)
        int s = i4 >> 10;
        int q = i4 & 1023;
        int row = q >> 3;
        int k4 = q & 7;
        float4 v = ((const float4*)fc1_w)[row * 784 + s * 8 + k4];
        u16x4 o;
        o[0] = f2bf_hw(v.x);
        o[1] = f2bf_hw(v.y);
        o[2] = f2bf_hw(v.z);
        o[3] = f2bf_hw(v.w);
        ((u16x4*)wbf)[(size_t)s * 1024 + row * 8 + k4] = o;
    }
}

// ---------------------------------------------------------------------------
// Fused conv, ONE image per 256-thread block (4 waves).
// conv1 16x16x16 MFMA (2-deep pipelined LDS gather); conv2 32x32x16 MFMA,
// B preloaded to registers before conv1.
// a2 output K-TILED [98][4096][32]: image n's k-chunk s (32 halfs = 64B)
// lands at a2 + (s*4096 + n)*32, so fc's A-loads are wave-contiguous.
// img16 stride 36 halfs: conv1 gather conflict-free.
// ---------------------------------------------------------------------------
__global__ __launch_bounds__(256) void fused_conv_kernel(
        const float* __restrict__ x, const _Float16* __restrict__ w1h,
        const _Float16* __restrict__ w2h, const float* __restrict__ conv2_b,
        u16* __restrict__ a2) {
    __shared__ _Float16 img16[30][36];
    __shared__ __align__(16) _Float16 a1s[16][16][40];
    __shared__ __align__(16) u16 out2[64 * 49];

    int t = threadIdx.x;
    int n = blockIdx.x;
    int lane = t & 63;
    int w = t >> 6;                    // wave 0..3
    int l16 = lane & 15;
    int quad = lane >> 4;
    int l32 = lane & 31;
    int h = lane >> 5;

    // ---- conv2 B-fragment preload (global/L2), latency hidden by conv1 ----
    int nt = w & 1;
    int mt0 = w >> 1;
    int oc = nt * 32 + l32;
    half8 bE[9], bO[9];
    const _Float16* bp = w2h + (size_t)oc * 32 + h * 8;
#pragma unroll
    for (int tt = 0; tt < 9; ++tt) {
        bE[tt] = *(const half8*)(bp + tt * 2048);
        bO[tt] = *(const half8*)(bp + tt * 2048 + 16);
    }
    float bias = conv2_b[oc];

    // ---- phase 1 (single barrier): a1s ring-zero + img16 fill ----
    for (int i = t; i < 240; i += 256) {
        int pos = i >> 2, ch = i & 3;
        int r, c;
        if (pos < 16)      { r = 0;        c = pos; }
        else if (pos < 32) { r = 15;       c = pos - 16; }
        else if (pos < 46) { r = pos - 31; c = 0; }
        else               { r = pos - 45; c = 15; }
        *(int4*)&a1s[r][c][ch * 8] = int4{0, 0, 0, 0};
    }
    const float* xim = x + (size_t)n * 784;
    for (int i = t; i < 960; i += 256) {
        int r = i >> 5, c = i & 31;
        bool inter = (r >= 1) & (r <= 28) & (c >= 1) & (c <= 28);
        float v = inter ? xim[(r - 1) * 28 + (c - 1)] : 0.0f;
        img16[r][c] = (_Float16)v;
    }
    __syncthreads();

    // ---- conv1 MFMA: M pool-major, N=32, K=16 (taps >=9 clamped; B rows
    //      zero there so garbage A values contribute nothing) ----
    half4 b1a = *(const half4*)&w1h[l16 * 16 + quad * 4];
    half4 b1b = *(const half4*)&w1h[(16 + l16) * 16 + quad * 4];
    int t0 = quad * 4;
    int u0 = t0 < 9 ? t0 : 8, u1 = t0 + 1 < 9 ? t0 + 1 : 8;
    int u2 = t0 + 2 < 9 ? t0 + 2 : 8, u3 = t0 + 3 < 9 ? t0 + 3 : 8;
    int off0 = (u0 / 3) * 36 + (u0 % 3);
    int off1 = (u1 / 3) * 36 + (u1 % 3);
    int off2 = (u2 / 3) * 36 + (u2 % 3);
    int off3 = (u3 / 3) * 36 + (u3 % 3);
    int sy = (l16 & 3) >> 1, sx = l16 & 1;

    int pool0 = w * 4 + (l16 >> 2);
    int a14 = pool0 >= 14 ? 1 : 0;
    int b14 = pool0 - 14 * a14;
    int pl0 = w * 4 + quad;
    int pa = pl0 >= 14 ? 1 : 0;
    int pb = pl0 - 14 * pa;

    const _Float16* p0 = &img16[2 * a14 + sy][2 * b14 + sx];
    half4 avc;
    avc[0] = p0[off0];
    avc[1] = p0[off1];
    avc[2] = p0[off2];
    avc[3] = p0[off3];

    for (int mt = w; mt < 49; mt += 4) {
        a14 += 1; b14 += 2;
        if (b14 >= 14) { b14 -= 14; a14 += 1; }
        half4 avn;
        if (mt + 4 < 49) {
            const _Float16* p = &img16[2 * a14 + sy][2 * b14 + sx];
            avn[0] = p[off0];
            avn[1] = p[off1];
            avn[2] = p[off2];
            avn[3] = p[off3];
        }
        floatx4 c0 = {0.f, 0.f, 0.f, 0.f};
        floatx4 c1 = {0.f, 0.f, 0.f, 0.f};
        c0 = __builtin_amdgcn_mfma_f32_16x16x16f16(avc, b1a, c0, 0, 0, 0);
        c1 = __builtin_amdgcn_mfma_f32_16x16x16f16(avc, b1b, c1, 0, 0, 0);
        float m0 = fmaxf(fmaxf(c0[0], c0[1]), fmaxf(c0[2], c0[3]));
        float m1 = fmaxf(fmaxf(c1[0], c1[1]), fmaxf(c1[2], c1[3]));
        half2v pk;
        pk[0] = (_Float16)fmaxf(m0, 0.0f);    // channel l16    -> k=2*l16
        pk[1] = (_Float16)fmaxf(m1, 0.0f);    // channel l16+16 -> k=2*l16+1
        *(half2v*)&a1s[1 + pa][1 + pb][2 * l16] = pk;
        pa += 1; pb += 2;
        if (pb >= 14) { pb -= 14; pa += 1; }
        avc = avn;
    }
    __syncthreads();

    // ---- conv2 MFMA 32x32x16: nt fixed/wave, mts strided by 2; single
    //      accumulator chain ----
    for (int mt = mt0; mt < 7; mt += 2) {
        int pool = mt * 8 + (l32 >> 2);
        int sub = l32 & 3;
        int pc = pool < 49 ? pool : 48;
        int y = 2 * (pc / 7) + (sub >> 1);
        int xq = 2 * (pc % 7) + (sub & 1);
        const _Float16* ap = &a1s[y][xq][h * 8];
        floatx16 acc = {};
#pragma unroll
        for (int tt = 0; tt < 9; ++tt) {
            int ao = ((tt / 3) * 16 + (tt % 3)) * 40;
            half8 avE = *(const half8*)(ap + ao);
            half8 avO = *(const half8*)(ap + ao + 16);
            acc = __builtin_amdgcn_mfma_f32_32x32x16_f16(avE, bE[tt], acc,
                                                         0, 0, 0);
            acc = __builtin_amdgcn_mfma_f32_32x32x16_f16(avO, bO[tt], acc,
                                                         0, 0, 0);
        }
#pragma unroll
        for (int rg = 0; rg < 4; ++rg) {
            int pl = mt * 8 + 2 * rg + h;
            if (pl < 49) {
                float v0 = acc[rg * 4 + 0];
                float v1 = acc[rg * 4 + 1];
                float v2 = acc[rg * 4 + 2];
                float v3 = acc[rg * 4 + 3];
                float mx = fmaxf(fmaxf(v0, v1), fmaxf(v2, v3));
                out2[oc * 49 + pl] = f2bf_hw(fmaxf(mx + bias, 0.0f));
            }
        }
    }
    __syncthreads();

    // ---- K-tiled copy LDS -> a2: chunk s (8 uint2) to (s*4096+n)*32 ----
    uint2* dst = (uint2*)a2;
    const uint2* src = (const uint2*)&out2[0];
    size_t n8 = (size_t)n * 8;
    for (int i = t; i < 784; i += 256) {
        int s = i >> 3, off = i & 7;
        dst[(size_t)s * 32768 + n8 + off] = src[i];
    }
}

// ---------------------------------------------------------------------------
// fc1 + fc2, 256 blocks x 1024 thr, 16 images/block (16 waves = 8 strided
// K-eighths x 2 N-halves, 4 acc chains). K-tiled operands: every bs8 load
// is wave-contiguous 1KB (16 rows x 64B within one K-tile slab).
// a2t [98][4096][32]; wbf [98][128][32]. Hs[8] tree reduce, fc2 in-block.
// ---------------------------------------------------------------------------
__global__ __launch_bounds__(1024) void fc_kernel(
        const u16* __restrict__ A, const u16* __restrict__ Wbf,
        const float* __restrict__ fc1_b, const float* __restrict__ fc2_w,
        const float* __restrict__ fc2_b, float* __restrict__ out) {
    __shared__ float Hs[8][16][132];
    int tid = threadIdx.x;
    int lane = tid & 63;
    int w = tid >> 6;                  // 0..15
    int l16 = lane & 15;
    int quad = lane >> 4;
    int kq = w >> 1;                   // 0..7, strided K-eighth
    int nh = w & 1;                    // N-half
    int m0 = blockIdx.x * 16;

    const u16* abase = A + (size_t)(m0 + l16) * 32 + quad * 8;
    const u16* bbase = Wbf + (size_t)(nh * 64 + l16) * 32 + quad * 8;

    floatx4 ac0 = {0.f, 0.f, 0.f, 0.f};
    floatx4 ac1 = {0.f, 0.f, 0.f, 0.f};
    floatx4 ac2 = {0.f, 0.f, 0.f, 0.f};
    floatx4 ac3 = {0.f, 0.f, 0.f, 0.f};
#pragma unroll 4
    for (int s = kq; s < 98; s += 8) {
        bs8 av = *(const bs8*)(abase + (size_t)s * 131072);
        const u16* bt = bbase + (size_t)s * 4096;
        bs8 bv0 = *(const bs8*)(bt);
        bs8 bv1 = *(const bs8*)(bt + 512);
        bs8 bv2 = *(const bs8*)(bt + 1024);
        bs8 bv3 = *(const bs8*)(bt + 1536);
        ac0 = __builtin_amdgcn_mfma_f32_16x16x32_bf16(av, bv0, ac0, 0, 0, 0);
        ac1 = __builtin_amdgcn_mfma_f32_16x16x32_bf16(av, bv1, ac1, 0, 0, 0);
        ac2 = __builtin_amdgcn_mfma_f32_16x16x32_bf16(av, bv2, ac2, 0, 0, 0);
        ac3 = __builtin_amdgcn_mfma_f32_16x16x32_bf16(av, bv3, ac3, 0, 0, 0);
    }
    int nb = nh * 64 + l16;
#pragma unroll
    for (int r = 0; r < 4; ++r) {
        int mr = quad * 4 + r;
        Hs[kq][mr][nb] = ac0[r];
        Hs[kq][mr][nb + 16] = ac1[r];
        Hs[kq][mr][nb + 32] = ac2[r];
        Hs[kq][mr][nb + 48] = ac3[r];
    }
    __syncthreads();

    for (int i = tid; i < 2048; i += 1024) {
        int m = i >> 7, k = i & 127;
        float s = Hs[0][m][k] + Hs[1][m][k] + Hs[2][m][k] + Hs[3][m][k] +
                  Hs[4][m][k] + Hs[5][m][k] + Hs[6][m][k] + Hs[7][m][k];
        Hs[0][m][k] = s;
    }
    __syncthreads();

    if (tid < 160) {
        int m = tid / 10, j = tid % 10;
        const float* wr = fc2_w + j * 128;
        float acc = fc2_b[j];
#pragma unroll 16
        for (int k = 0; k < 128; ++k)
            acc += fmaxf(Hs[0][m][k] + fc1_b[k], 0.0f) * wr[k];
        out[(size_t)(m0 + m) * 10 + j] = acc;
    }
}

extern "C" void kernel_launch(void* const* d_in, const int* in_sizes, int n_in,
                              void* d_out, int out_size, void* d_ws,
                              size_t ws_size, hipStream_t stream) {
    const float* x       = (const float*)d_in[0];
    const float* theta   = (const float*)d_in[1];
    const float* sigma   = (const float*)d_in[2];
    const float* gamma   = (const float*)d_in[3];
    const float* lambd   = (const float*)d_in[4];
    const float* psi     = (const float*)d_in[5];
    const float* conv2_w = (const float*)d_in[6];
    const float* conv2_b = (const float*)d_in[7];
    const float* fc1_w   = (const float*)d_in[8];
    const float* fc1_b   = (const float*)d_in[9];
    const float* fc2_w   = (const float*)d_in[10];
    const float* fc2_b   = (const float*)d_in[11];
    float* out = (float*)d_out;

    // ws (26.53 MB, under the 27.07 proven-safe watermark):
    //   a2  bf16 K-tiled [98][4096][32] : 0          (25,690,112 B)
    //   w1h f16 [32][16]                : 25,690,112 (1,024 B)
    //   w2h f16 [9][64][32]             : 25,691,136 (36,864 B)
    //   wbf bf16 K-tiled [98][128][32]  : 25,728,000 (802,816 B)
    char* ws = (char*)d_ws;
    u16* a2 = (u16*)ws;
    _Float16* w1h = (_Float16*)(ws + 25690112ull);
    _Float16* w2h = (_Float16*)(ws + 25691136ull);
    u16* wbf = (u16*)(ws + 25728000ull);

    prep_kernel<<<466, 256, 0, stream>>>(theta, sigma, gamma, lambd, psi,
                                         conv2_w, fc1_w, w1h, w2h, wbf);
    fused_conv_kernel<<<BATCH, 256, 0, stream>>>(x, w1h, w2h, conv2_b, a2);
    fc_kernel<<<BATCH / 16, 1024, 0, stream>>>(a2, wbf, fc1_b, fc2_w, fc2_b,
                                               out);
}

// Round 6
// 148.760 us; speedup vs baseline: 1.2585x; 1.0051x over previous
//
#include <hip/hip_runtime.h>
#include <hip/hip_bf16.h>

#define BATCH 4096

typedef unsigned short u16;
typedef _Float16 half2v __attribute__((ext_vector_type(2)));
typedef _Float16 half4 __attribute__((ext_vector_type(4)));
typedef _Float16 half8 __attribute__((ext_vector_type(8)));
typedef short bs8 __attribute__((ext_vector_type(8)));
typedef u16 u16x4 __attribute__((ext_vector_type(4)));
typedef float floatx4 __attribute__((ext_vector_type(4)));
typedef float floatx16 __attribute__((ext_vector_type(16)));

__device__ inline u16 f2bf_hw(float f) {        // HW cvt (RNE)
    __hip_bfloat16 b = __float2bfloat16(f);
    return *(u16*)&b;
}

// ---------------------------------------------------------------------------
// Prep (466 blocks exact): w1h gabor f16 [32][16] (K 9->16 zero-pad);
// w2h f16 [tap][oc][k] ic-interleaved (k=2c+p <-> channel c+16p);
// wbf bf16 K-TILED [98][128][32] in k' = pl*64 + oc order (pl-major, matching
// fused's out2 layout): fc's B-loads stay wave-contiguous 1KB.
// ---------------------------------------------------------------------------
__global__ __launch_bounds__(256) void prep_kernel(
        const float* __restrict__ theta, const float* __restrict__ sigma,
        const float* __restrict__ gamma, const float* __restrict__ lambd,
        const float* __restrict__ psi, const float* __restrict__ conv2_w,
        const float* __restrict__ fc1_w, _Float16* __restrict__ w1h,
        _Float16* __restrict__ w2h, u16* __restrict__ wbf) {
    int id = blockIdx.x * 256 + threadIdx.x;
    if (id < 512) {
        int g = id >> 4, t = id & 15;
        float v = 0.0f;
        if (t < 9) {
            int i = t / 3, j = t % 3;
            float xg = (float)i - 1.0f;      // meshgrid 'ij'
            float yg = (float)j - 1.0f;
            if (g < 16) {
                float th = theta[g];
                float c = cosf(th), s = sinf(th);
                float xt = xg * c + yg * s;
                float yt = -xg * s + yg * c;
                float sx = sigma[g];
                float sy = sx / gamma[g];
                float env = expf(-0.5f *
                                 (xt * xt / (sx * sx) + yt * yt / (sy * sy)));
                float car =
                    cosf(6.28318530717958647692f * xt / lambd[g] + psi[g]);
                v = env * car;
            } else {
                v = (t == 4) ? 1.0f : 0.0f;
            }
        }
        w1h[id] = (_Float16)v;
    } else if (id < 512 + 18432) {
        int t2 = id - 512;
        int tap = t2 / 2048, rem = t2 % 2048;
        int oc = rem / 32, k = rem % 32;
        int ic = (k >> 1) + 16 * (k & 1);     // interleaved channel order
        w2h[t2] = (_Float16)conv2_w[(oc * 32 + ic) * 9 + tap];
    } else {
        // wbf in k' = pl*64+oc order: dst u16x4 [s][row][q&7] covers
        // k' = s*32 + (q&7)*4 + e; oc = k'&63, pl = k'>>6 (constant over e).
        // src = fc1_w[row*3136 + oc*49 + pl], stride 49 floats over e.
        int i4 = id - 18944;                  // < 100352 (grid exact)
        int s = i4 >> 10;
        int q = i4 & 1023;
        int row = q >> 3;
        int kp = s * 32 + (q & 7) * 4;        // k' base
        int pl = kp >> 6;
        int ocb = kp & 63;
        const float* src = fc1_w + row * 3136 + ocb * 49 + pl;
        u16x4 o;
        o[0] = f2bf_hw(src[0]);
        o[1] = f2bf_hw(src[49]);
        o[2] = f2bf_hw(src[98]);
        o[3] = f2bf_hw(src[147]);
        ((u16x4*)wbf)[(size_t)s * 1024 + row * 8 + (q & 7)] = o;
    }
}

// ---------------------------------------------------------------------------
// Fused conv, ONE image per 256-thread block (4 waves).
// Register-budget round: conv2 B-fragments (bE/bO = 72 regs) loaded AFTER
// conv1 (live range = conv2 only; L2 latency overlaps the conv1->conv2
// barrier). __launch_bounds__(256,4) caps unified regs at 128 -> 4
// waves/SIMD (was ~148 -> 3). conv1 gather reverted to simple in-loop form.
// out2 pl-major [pl*64+oc]: lane-consecutive u16 writes are contiguous
// (<=2-way banks, free) and out2 is k'-linear so copy-out is unchanged.
// a2 output K-TILED [98][4096][32] in k' order.
// img16 stride 36 halfs: conv1 gather conflict-free.
// ---------------------------------------------------------------------------
__global__ __launch_bounds__(256, 4) void fused_conv_kernel(
        const float* __restrict__ x, const _Float16* __restrict__ w1h,
        const _Float16* __restrict__ w2h, const float* __restrict__ conv2_b,
        u16* __restrict__ a2) {
    __shared__ _Float16 img16[30][36];
    __shared__ __align__(16) _Float16 a1s[16][16][40];
    __shared__ __align__(16) u16 out2[64 * 49];

    int t = threadIdx.x;
    int n = blockIdx.x;
    int lane = t & 63;
    int w = t >> 6;                    // wave 0..3
    int l16 = lane & 15;
    int quad = lane >> 4;
    int l32 = lane & 31;
    int h = lane >> 5;

    int nt = w & 1;
    int mt0 = w >> 1;
    int oc = nt * 32 + l32;

    // ---- phase 1 (single barrier): a1s ring-zero + img16 fill ----
    for (int i = t; i < 240; i += 256) {
        int pos = i >> 2, ch = i & 3;
        int r, c;
        if (pos < 16)      { r = 0;        c = pos; }
        else if (pos < 32) { r = 15;       c = pos - 16; }
        else if (pos < 46) { r = pos - 31; c = 0; }
        else               { r = pos - 45; c = 15; }
        *(int4*)&a1s[r][c][ch * 8] = int4{0, 0, 0, 0};
    }
    const float* xim = x + (size_t)n * 784;
    for (int i = t; i < 960; i += 256) {
        int r = i >> 5, c = i & 31;
        bool inter = (r >= 1) & (r <= 28) & (c >= 1) & (c <= 28);
        float v = inter ? xim[(r - 1) * 28 + (c - 1)] : 0.0f;
        img16[r][c] = (_Float16)v;
    }
    __syncthreads();

    // ---- conv1 MFMA: M pool-major, N=32, K=16 (taps >=9 clamped; B rows
    //      zero there so garbage A values contribute nothing) ----
    half4 b1a = *(const half4*)&w1h[l16 * 16 + quad * 4];
    half4 b1b = *(const half4*)&w1h[(16 + l16) * 16 + quad * 4];
    int t0 = quad * 4;
    int u0 = t0 < 9 ? t0 : 8, u1 = t0 + 1 < 9 ? t0 + 1 : 8;
    int u2 = t0 + 2 < 9 ? t0 + 2 : 8, u3 = t0 + 3 < 9 ? t0 + 3 : 8;
    int off0 = (u0 / 3) * 36 + (u0 % 3);
    int off1 = (u1 / 3) * 36 + (u1 % 3);
    int off2 = (u2 / 3) * 36 + (u2 % 3);
    int off3 = (u3 / 3) * 36 + (u3 % 3);
    int sy = (l16 & 3) >> 1, sx = l16 & 1;

    int pool0 = w * 4 + (l16 >> 2);
    int a14 = pool0 >= 14 ? 1 : 0;
    int b14 = pool0 - 14 * a14;
    int pl0 = w * 4 + quad;
    int pa = pl0 >= 14 ? 1 : 0;
    int pb = pl0 - 14 * pa;

    for (int mt = w; mt < 49; mt += 4) {
        const _Float16* p = &img16[2 * a14 + sy][2 * b14 + sx];
        half4 av;
        av[0] = p[off0];
        av[1] = p[off1];
        av[2] = p[off2];
        av[3] = p[off3];
        floatx4 c0 = {0.f, 0.f, 0.f, 0.f};
        floatx4 c1 = {0.f, 0.f, 0.f, 0.f};
        c0 = __builtin_amdgcn_mfma_f32_16x16x16f16(av, b1a, c0, 0, 0, 0);
        c1 = __builtin_amdgcn_mfma_f32_16x16x16f16(av, b1b, c1, 0, 0, 0);
        float m0 = fmaxf(fmaxf(c0[0], c0[1]), fmaxf(c0[2], c0[3]));
        float m1 = fmaxf(fmaxf(c1[0], c1[1]), fmaxf(c1[2], c1[3]));
        half2v pk;
        pk[0] = (_Float16)fmaxf(m0, 0.0f);    // channel l16    -> k=2*l16
        pk[1] = (_Float16)fmaxf(m1, 0.0f);    // channel l16+16 -> k=2*l16+1
        *(half2v*)&a1s[1 + pa][1 + pb][2 * l16] = pk;
        a14 += 1; b14 += 2;
        if (b14 >= 14) { b14 -= 14; a14 += 1; }
        pa += 1; pb += 2;
        if (pb >= 14) { pb -= 14; pa += 1; }
    }

    // ---- conv2 B-fragment preload, AFTER conv1 (short live range; L2
    //      latency hidden by the barrier below) ----
    half8 bE[9], bO[9];
    const _Float16* bp = w2h + (size_t)oc * 32 + h * 8;
#pragma unroll
    for (int tt = 0; tt < 9; ++tt) {
        bE[tt] = *(const half8*)(bp + tt * 2048);
        bO[tt] = *(const half8*)(bp + tt * 2048 + 16);
    }
    float bias = conv2_b[oc];
    __syncthreads();

    // ---- conv2 MFMA 32x32x16: nt fixed/wave, mts strided by 2; single
    //      accumulator chain ----
    for (int mt = mt0; mt < 7; mt += 2) {
        int pool = mt * 8 + (l32 >> 2);
        int sub = l32 & 3;
        int pc = pool < 49 ? pool : 48;
        int y = 2 * (pc / 7) + (sub >> 1);
        int xq = 2 * (pc % 7) + (sub & 1);
        const _Float16* ap = &a1s[y][xq][h * 8];
        floatx16 acc = {};
#pragma unroll
        for (int tt = 0; tt < 9; ++tt) {
            int ao = ((tt / 3) * 16 + (tt % 3)) * 40;
            half8 avE = *(const half8*)(ap + ao);
            half8 avO = *(const half8*)(ap + ao + 16);
            acc = __builtin_amdgcn_mfma_f32_32x32x16_f16(avE, bE[tt], acc,
                                                         0, 0, 0);
            acc = __builtin_amdgcn_mfma_f32_32x32x16_f16(avO, bO[tt], acc,
                                                         0, 0, 0);
        }
#pragma unroll
        for (int rg = 0; rg < 4; ++rg) {
            int pl = mt * 8 + 2 * rg + h;
            if (pl < 49) {
                float v0 = acc[rg * 4 + 0];
                float v1 = acc[rg * 4 + 1];
                float v2 = acc[rg * 4 + 2];
                float v3 = acc[rg * 4 + 3];
                float mx = fmaxf(fmaxf(v0, v1), fmaxf(v2, v3));
                out2[pl * 64 + oc] = f2bf_hw(fmaxf(mx + bias, 0.0f));
            }
        }
    }
    __syncthreads();

    // ---- K-tiled copy LDS -> a2 (out2 is k'-linear): chunk s (8 uint2)
    //      to (s*4096+n)*32 ----
    uint2* dst = (uint2*)a2;
    const uint2* src = (const uint2*)&out2[0];
    size_t n8 = (size_t)n * 8;
    for (int i = t; i < 784; i += 256) {
        int s = i >> 3, off = i & 7;
        dst[(size_t)s * 32768 + n8 + off] = src[i];
    }
}

// ---------------------------------------------------------------------------
// fc1 + fc2, 256 blocks x 1024 thr, 16 images/block (16 waves = 8 strided
// K-eighths x 2 N-halves, 4 acc chains). K-tiled operands: every bs8 load
// is wave-contiguous 1KB (16 rows x 64B within one K-tile slab).
// a2t [98][4096][32]; wbf [98][128][32]; both in k' order (consistent).
// ---------------------------------------------------------------------------
__global__ __launch_bounds__(1024) void fc_kernel(
        const u16* __restrict__ A, const u16* __restrict__ Wbf,
        const float* __restrict__ fc1_b, const float* __restrict__ fc2_w,
        const float* __restrict__ fc2_b, float* __restrict__ out) {
    __shared__ float Hs[8][16][132];
    int tid = threadIdx.x;
    int lane = tid & 63;
    int w = tid >> 6;                  // 0..15
    int l16 = lane & 15;
    int quad = lane >> 4;
    int kq = w >> 1;                   // 0..7, strided K-eighth
    int nh = w & 1;                    // N-half
    int m0 = blockIdx.x * 16;

    const u16* abase = A + (size_t)(m0 + l16) * 32 + quad * 8;
    const u16* bbase = Wbf + (size_t)(nh * 64 + l16) * 32 + quad * 8;

    floatx4 ac0 = {0.f, 0.f, 0.f, 0.f};
    floatx4 ac1 = {0.f, 0.f, 0.f, 0.f};
    floatx4 ac2 = {0.f, 0.f, 0.f, 0.f};
    floatx4 ac3 = {0.f, 0.f, 0.f, 0.f};
#pragma unroll 4
    for (int s = kq; s < 98; s += 8) {
        bs8 av = *(const bs8*)(abase + (size_t)s * 131072);
        const u16* bt = bbase + (size_t)s * 4096;
        bs8 bv0 = *(const bs8*)(bt);
        bs8 bv1 = *(const bs8*)(bt + 512);
        bs8 bv2 = *(const bs8*)(bt + 1024);
        bs8 bv3 = *(const bs8*)(bt + 1536);
        ac0 = __builtin_amdgcn_mfma_f32_16x16x32_bf16(av, bv0, ac0, 0, 0, 0);
        ac1 = __builtin_amdgcn_mfma_f32_16x16x32_bf16(av, bv1, ac1, 0, 0, 0);
        ac2 = __builtin_amdgcn_mfma_f32_16x16x32_bf16(av, bv2, ac2, 0, 0, 0);
        ac3 = __builtin_amdgcn_mfma_f32_16x16x32_bf16(av, bv3, ac3, 0, 0, 0);
    }
    int nb = nh * 64 + l16;
#pragma unroll
    for (int r = 0; r < 4; ++r) {
        int mr = quad * 4 + r;
        Hs[kq][mr][nb] = ac0[r];
        Hs[kq][mr][nb + 16] = ac1[r];
        Hs[kq][mr][nb + 32] = ac2[r];
        Hs[kq][mr][nb + 48] = ac3[r];
    }
    __syncthreads();

    for (int i = tid; i < 2048; i += 1024) {
        int m = i >> 7, k = i & 127;
        float s = Hs[0][m][k] + Hs[1][m][k] + Hs[2][m][k] + Hs[3][m][k] +
                  Hs[4][m][k] + Hs[5][m][k] + Hs[6][m][k] + Hs[7][m][k];
        Hs[0][m][k] = s;
    }
    __syncthreads();

    if (tid < 160) {
        int m = tid / 10, j = tid % 10;
        const float* wr = fc2_w + j * 128;
        float acc = fc2_b[j];
#pragma unroll 16
        for (int k = 0; k < 128; ++k)
            acc += fmaxf(Hs[0][m][k] + fc1_b[k], 0.0f) * wr[k];
        out[(size_t)(m0 + m) * 10 + j] = acc;
    }
}

extern "C" void kernel_launch(void* const* d_in, const int* in_sizes, int n_in,
                              void* d_out, int out_size, void* d_ws,
                              size_t ws_size, hipStream_t stream) {
    const float* x       = (const float*)d_in[0];
    const float* theta   = (const float*)d_in[1];
    const float* sigma   = (const float*)d_in[2];
    const float* gamma   = (const float*)d_in[3];
    const float* lambd   = (const float*)d_in[4];
    const float* psi     = (const float*)d_in[5];
    const float* conv2_w = (const float*)d_in[6];
    const float* conv2_b = (const float*)d_in[7];
    const float* fc1_w   = (const float*)d_in[8];
    const float* fc1_b   = (const float*)d_in[9];
    const float* fc2_w   = (const float*)d_in[10];
    const float* fc2_b   = (const float*)d_in[11];
    float* out = (float*)d_out;

    // ws (26.53 MB, under the 27.07 proven-safe watermark):
    //   a2  bf16 K-tiled [98][4096][32] : 0          (25,690,112 B)
    //   w1h f16 [32][16]                : 25,690,112 (1,024 B)
    //   w2h f16 [9][64][32]             : 25,691,136 (36,864 B)
    //   wbf bf16 K-tiled [98][128][32]  : 25,728,000 (802,816 B)
    char* ws = (char*)d_ws;
    u16* a2 = (u16*)ws;
    _Float16* w1h = (_Float16*)(ws + 25690112ull);
    _Float16* w2h = (_Float16*)(ws + 25691136ull);
    u16* wbf = (u16*)(ws + 25728000ull);

    prep_kernel<<<466, 256, 0, stream>>>(theta, sigma, gamma, lambd, psi,
                                         conv2_w, fc1_w, w1h, w2h, wbf);
    fused_conv_kernel<<<BATCH, 256, 0, stream>>>(x, w1h, w2h, conv2_b, a2);
    fc_kernel<<<BATCH / 16, 1024, 0, stream>>>(a2, wbf, fc1_b, fc2_w, fc2_b,
                                               out);
}

// Round 7
// 145.658 us; speedup vs baseline: 1.2853x; 1.0213x over previous
//
#include <hip/hip_runtime.h>
#include <hip/hip_bf16.h>

#define BATCH 4096

typedef unsigned short u16;
typedef _Float16 half2v __attribute__((ext_vector_type(2)));
typedef _Float16 half4 __attribute__((ext_vector_type(4)));
typedef _Float16 half8 __attribute__((ext_vector_type(8)));
typedef short bs8 __attribute__((ext_vector_type(8)));
typedef u16 u16x4 __attribute__((ext_vector_type(4)));
typedef float floatx4 __attribute__((ext_vector_type(4)));
typedef float floatx16 __attribute__((ext_vector_type(16)));

__device__ inline u16 f2bf_hw(float f) {        // HW cvt (RNE)
    __hip_bfloat16 b = __float2bfloat16(f);
    return *(u16*)&b;
}

// ---------------------------------------------------------------------------
// Prep (466 blocks exact): w1h gabor f16 [32][16] (K 9->16 zero-pad);
// w2h f16 [tap][oc][k] ic-interleaved (k=2c+p <-> channel c+16p);
// wbf bf16 K-TILED [98][128][32] in k' = pl*64 + oc order (pl-major, matching
// fused's out2 layout): fc's B-loads stay wave-contiguous 1KB.
// ---------------------------------------------------------------------------
__global__ __launch_bounds__(256) void prep_kernel(
        const float* __restrict__ theta, const float* __restrict__ sigma,
        const float* __restrict__ gamma, const float* __restrict__ lambd,
        const float* __restrict__ psi, const float* __restrict__ conv2_w,
        const float* __restrict__ fc1_w, _Float16* __restrict__ w1h,
        _Float16* __restrict__ w2h, u16* __restrict__ wbf) {
    int id = blockIdx.x * 256 + threadIdx.x;
    if (id < 512) {
        int g = id >> 4, t = id & 15;
        float v = 0.0f;
        if (t < 9) {
            int i = t / 3, j = t % 3;
            float xg = (float)i - 1.0f;      // meshgrid 'ij'
            float yg = (float)j - 1.0f;
            if (g < 16) {
                float th = theta[g];
                float c = cosf(th), s = sinf(th);
                float xt = xg * c + yg * s;
                float yt = -xg * s + yg * c;
                float sx = sigma[g];
                float sy = sx / gamma[g];
                float env = expf(-0.5f *
                                 (xt * xt / (sx * sx) + yt * yt / (sy * sy)));
                float car =
                    cosf(6.28318530717958647692f * xt / lambd[g] + psi[g]);
                v = env * car;
            } else {
                v = (t == 4) ? 1.0f : 0.0f;
            }
        }
        w1h[id] = (_Float16)v;
    } else if (id < 512 + 18432) {
        int t2 = id - 512;
        int tap = t2 / 2048, rem = t2 % 2048;
        int oc = rem / 32, k = rem % 32;
        int ic = (k >> 1) + 16 * (k & 1);     // interleaved channel order
        w2h[t2] = (_Float16)conv2_w[(oc * 32 + ic) * 9 + tap];
    } else {
        // wbf in k' = pl*64+oc order: dst u16x4 [s][row][q&7] covers
        // k' = s*32 + (q&7)*4 + e; oc = k'&63, pl = k'>>6 (constant over e).
        // src = fc1_w[row*3136 + oc*49 + pl], stride 49 floats over e.
        int i4 = id - 18944;                  // < 100352 (grid exact)
        int s = i4 >> 10;
        int q = i4 & 1023;
        int row = q >> 3;
        int kp = s * 32 + (q & 7) * 4;        // k' base
        int pl = kp >> 6;
        int ocb = kp & 63;
        const float* src = fc1_w + row * 3136 + ocb * 49 + pl;
        u16x4 o;
        o[0] = f2bf_hw(src[0]);
        o[1] = f2bf_hw(src[49]);
        o[2] = f2bf_hw(src[98]);
        o[3] = f2bf_hw(src[147]);
        ((u16x4*)wbf)[(size_t)s * 1024 + row * 8 + (q & 7)] = o;
    }
}

// ---------------------------------------------------------------------------
// Fused conv, TWO images SEQUENTIALLY per 256-thread block (grid 2048).
// Amortizes per-image fixed cost: preamble, w1h fragments, conv1 offset
// setup, conv2 B-fragments (bE/bO, 72 regs from w2h) and bias load happen
// ONCE per block. Image 1's global x-load issues at the top of image 0's
// conv1 (4 regs) and is LDS-written during image 0's conv2 -> HBM latency
// fully hidden. 5 barriers / 2 images (was 6). a1s ring + img16 border
// zeroed once (interiors fully rewritten each image).
// out2 pl-major [pl*64+oc]; a2 K-TILED [98][4096][32] in k' order.
// img16 stride 36 halfs: conv1 gather conflict-free.
// ---------------------------------------------------------------------------
__global__ __launch_bounds__(256, 4) void fused_conv_kernel(
        const float* __restrict__ x, const _Float16* __restrict__ w1h,
        const _Float16* __restrict__ w2h, const float* __restrict__ conv2_b,
        u16* __restrict__ a2) {
    __shared__ _Float16 img16[30][36];
    __shared__ __align__(16) _Float16 a1s[16][16][40];
    __shared__ __align__(16) u16 out2[64 * 49];

    int t = threadIdx.x;
    int n0 = blockIdx.x * 2;
    int lane = t & 63;
    int w = t >> 6;                    // wave 0..3
    int l16 = lane & 15;
    int quad = lane >> 4;
    int l32 = lane & 31;
    int h = lane >> 5;

    int nt = w & 1;
    int mt0 = w >> 1;
    int oc = nt * 32 + l32;

    // ---- preamble (image-independent, once per block) ----
    half4 b1a = *(const half4*)&w1h[l16 * 16 + quad * 4];
    half4 b1b = *(const half4*)&w1h[(16 + l16) * 16 + quad * 4];
    int t0 = quad * 4;
    int u0 = t0 < 9 ? t0 : 8, u1 = t0 + 1 < 9 ? t0 + 1 : 8;
    int u2 = t0 + 2 < 9 ? t0 + 2 : 8, u3 = t0 + 3 < 9 ? t0 + 3 : 8;
    int off0 = (u0 / 3) * 36 + (u0 % 3);
    int off1 = (u1 / 3) * 36 + (u1 % 3);
    int off2 = (u2 / 3) * 36 + (u2 % 3);
    int off3 = (u3 / 3) * 36 + (u3 % 3);
    int sy = (l16 & 3) >> 1, sx = l16 & 1;

    int pool0 = w * 4 + (l16 >> 2);
    int a14_s = pool0 >= 14 ? 1 : 0;
    int b14_s = pool0 - 14 * a14_s;
    int pl0 = w * 4 + quad;
    int pa_s = pl0 >= 14 ? 1 : 0;
    int pb_s = pl0 - 14 * pa_s;

    // conv1: reads img16, writes a1s interior
    auto conv1_body = [&]() {
        int a14 = a14_s, b14 = b14_s, pa = pa_s, pb = pb_s;
        for (int mt = w; mt < 49; mt += 4) {
            const _Float16* p = &img16[2 * a14 + sy][2 * b14 + sx];
            half4 av;
            av[0] = p[off0];
            av[1] = p[off1];
            av[2] = p[off2];
            av[3] = p[off3];
            floatx4 c0 = {0.f, 0.f, 0.f, 0.f};
            floatx4 c1 = {0.f, 0.f, 0.f, 0.f};
            c0 = __builtin_amdgcn_mfma_f32_16x16x16f16(av, b1a, c0, 0, 0, 0);
            c1 = __builtin_amdgcn_mfma_f32_16x16x16f16(av, b1b, c1, 0, 0, 0);
            float m0 = fmaxf(fmaxf(c0[0], c0[1]), fmaxf(c0[2], c0[3]));
            float m1 = fmaxf(fmaxf(c1[0], c1[1]), fmaxf(c1[2], c1[3]));
            half2v pk;
            pk[0] = (_Float16)fmaxf(m0, 0.0f);    // ch l16    -> k=2*l16
            pk[1] = (_Float16)fmaxf(m1, 0.0f);    // ch l16+16 -> k=2*l16+1
            *(half2v*)&a1s[1 + pa][1 + pb][2 * l16] = pk;
            a14 += 1; b14 += 2;
            if (b14 >= 14) { b14 -= 14; a14 += 1; }
            pa += 1; pb += 2;
            if (pb >= 14) { pb -= 14; pa += 1; }
        }
    };

    // ---- S0: img0 fill (select-based; zeroes border once) + a1s ring ----
    if (t < 240) {
        int pos = t >> 2, ch = t & 3;
        int r, c;
        if (pos < 16)      { r = 0;        c = pos; }
        else if (pos < 32) { r = 15;       c = pos - 16; }
        else if (pos < 46) { r = pos - 31; c = 0; }
        else               { r = pos - 45; c = 15; }
        *(int4*)&a1s[r][c][ch * 8] = int4{0, 0, 0, 0};
    }
    const float* xim0 = x + (size_t)n0 * 784;
    for (int i = t; i < 960; i += 256) {
        int r = i >> 5, c = i & 31;
        bool inter = (r >= 1) & (r <= 28) & (c >= 1) & (c <= 28);
        float v = inter ? xim0[(r - 1) * 28 + (c - 1)] : 0.0f;
        img16[r][c] = (_Float16)v;
    }
    __syncthreads();                                     // A

    // ---- S2: issue img1 x-loads, conv1(img0), B-preload ----
    const float* xim1 = x + (size_t)(n0 + 1) * 784;
    float gx[4];
#pragma unroll
    for (int j = 0; j < 4; ++j) {
        int i = t + j * 256;
        gx[j] = (i < 784) ? xim1[i] : 0.0f;
    }
    conv1_body();
    half8 bE[9], bO[9];
    {
        const _Float16* bp = w2h + (size_t)oc * 32 + h * 8;
#pragma unroll
        for (int tt = 0; tt < 9; ++tt) {
            bE[tt] = *(const half8*)(bp + tt * 2048);
            bO[tt] = *(const half8*)(bp + tt * 2048 + 16);
        }
    }
    float bias = conv2_b[oc];
    __syncthreads();                                     // B

    // conv2: reads a1s + bE/bO, writes out2 (pl-major)
    auto conv2_body = [&]() {
        for (int mt = mt0; mt < 7; mt += 2) {
            int pool = mt * 8 + (l32 >> 2);
            int sub = l32 & 3;
            int pc = pool < 49 ? pool : 48;
            int y = 2 * (pc / 7) + (sub >> 1);
            int xq = 2 * (pc % 7) + (sub & 1);
            const _Float16* ap = &a1s[y][xq][h * 8];
            floatx16 acc = {};
#pragma unroll
            for (int tt = 0; tt < 9; ++tt) {
                int ao = ((tt / 3) * 16 + (tt % 3)) * 40;
                half8 avE = *(const half8*)(ap + ao);
                half8 avO = *(const half8*)(ap + ao + 16);
                acc = __builtin_amdgcn_mfma_f32_32x32x16_f16(avE, bE[tt], acc,
                                                             0, 0, 0);
                acc = __builtin_amdgcn_mfma_f32_32x32x16_f16(avO, bO[tt], acc,
                                                             0, 0, 0);
            }
#pragma unroll
            for (int rg = 0; rg < 4; ++rg) {
                int pl = mt * 8 + 2 * rg + h;
                if (pl < 49) {
                    float v0 = acc[rg * 4 + 0];
                    float v1 = acc[rg * 4 + 1];
                    float v2 = acc[rg * 4 + 2];
                    float v3 = acc[rg * 4 + 3];
                    float mx = fmaxf(fmaxf(v0, v1), fmaxf(v2, v3));
                    out2[pl * 64 + oc] = f2bf_hw(fmaxf(mx + bias, 0.0f));
                }
            }
        }
    };

    // copy-out: K-tiled a2 (out2 is k'-linear): chunk s (8 uint2)
    auto copyout = [&](int n) {
        uint2* dst = (uint2*)a2;
        const uint2* src = (const uint2*)&out2[0];
        size_t n8 = (size_t)n * 8;
        for (int i = t; i < 784; i += 256) {
            int s = i >> 3, off = i & 7;
            dst[(size_t)s * 32768 + n8 + off] = src[i];
        }
    };

    // ---- S3: img16 <- img1 (from regs), conv2(img0) ----
#pragma unroll
    for (int j = 0; j < 4; ++j) {
        int i = t + j * 256;
        if (i < 784) img16[i / 28 + 1][i % 28 + 1] = (_Float16)gx[j];
    }
    conv2_body();
    __syncthreads();                                     // C

    // ---- S4: copy-out(img0), conv1(img1) ----
    copyout(n0);
    conv1_body();
    __syncthreads();                                     // D

    // ---- S5: conv2(img1) ----
    conv2_body();
    __syncthreads();                                     // E

    // ---- S6: copy-out(img1) ----
    copyout(n0 + 1);
}

// ---------------------------------------------------------------------------
// fc1 + fc2, 256 blocks x 1024 thr, 16 images/block (16 waves = 8 strided
// K-eighths x 2 N-halves, 4 acc chains). K-tiled operands: every bs8 load
// is wave-contiguous 1KB (16 rows x 64B within one K-tile slab).
// a2t [98][4096][32]; wbf [98][128][32]; both in k' order (consistent).
// ---------------------------------------------------------------------------
__global__ __launch_bounds__(1024) void fc_kernel(
        const u16* __restrict__ A, const u16* __restrict__ Wbf,
        const float* __restrict__ fc1_b, const float* __restrict__ fc2_w,
        const float* __restrict__ fc2_b, float* __restrict__ out) {
    __shared__ float Hs[8][16][132];
    int tid = threadIdx.x;
    int lane = tid & 63;
    int w = tid >> 6;                  // 0..15
    int l16 = lane & 15;
    int quad = lane >> 4;
    int kq = w >> 1;                   // 0..7, strided K-eighth
    int nh = w & 1;                    // N-half
    int m0 = blockIdx.x * 16;

    const u16* abase = A + (size_t)(m0 + l16) * 32 + quad * 8;
    const u16* bbase = Wbf + (size_t)(nh * 64 + l16) * 32 + quad * 8;

    floatx4 ac0 = {0.f, 0.f, 0.f, 0.f};
    floatx4 ac1 = {0.f, 0.f, 0.f, 0.f};
    floatx4 ac2 = {0.f, 0.f, 0.f, 0.f};
    floatx4 ac3 = {0.f, 0.f, 0.f, 0.f};
#pragma unroll 4
    for (int s = kq; s < 98; s += 8) {
        bs8 av = *(const bs8*)(abase + (size_t)s * 131072);
        const u16* bt = bbase + (size_t)s * 4096;
        bs8 bv0 = *(const bs8*)(bt);
        bs8 bv1 = *(const bs8*)(bt + 512);
        bs8 bv2 = *(const bs8*)(bt + 1024);
        bs8 bv3 = *(const bs8*)(bt + 1536);
        ac0 = __builtin_amdgcn_mfma_f32_16x16x32_bf16(av, bv0, ac0, 0, 0, 0);
        ac1 = __builtin_amdgcn_mfma_f32_16x16x32_bf16(av, bv1, ac1, 0, 0, 0);
        ac2 = __builtin_amdgcn_mfma_f32_16x16x32_bf16(av, bv2, ac2, 0, 0, 0);
        ac3 = __builtin_amdgcn_mfma_f32_16x16x32_bf16(av, bv3, ac3, 0, 0, 0);
    }
    int nb = nh * 64 + l16;
#pragma unroll
    for (int r = 0; r < 4; ++r) {
        int mr = quad * 4 + r;
        Hs[kq][mr][nb] = ac0[r];
        Hs[kq][mr][nb + 16] = ac1[r];
        Hs[kq][mr][nb + 32] = ac2[r];
        Hs[kq][mr][nb + 48] = ac3[r];
    }
    __syncthreads();

    for (int i = tid; i < 2048; i += 1024) {
        int m = i >> 7, k = i & 127;
        float s = Hs[0][m][k] + Hs[1][m][k] + Hs[2][m][k] + Hs[3][m][k] +
                  Hs[4][m][k] + Hs[5][m][k] + Hs[6][m][k] + Hs[7][m][k];
        Hs[0][m][k] = s;
    }
    __syncthreads();

    if (tid < 160) {
        int m = tid / 10, j = tid % 10;
        const float* wr = fc2_w + j * 128;
        float acc = fc2_b[j];
#pragma unroll 16
        for (int k = 0; k < 128; ++k)
            acc += fmaxf(Hs[0][m][k] + fc1_b[k], 0.0f) * wr[k];
        out[(size_t)(m0 + m) * 10 + j] = acc;
    }
}

extern "C" void kernel_launch(void* const* d_in, const int* in_sizes, int n_in,
                              void* d_out, int out_size, void* d_ws,
                              size_t ws_size, hipStream_t stream) {
    const float* x       = (const float*)d_in[0];
    const float* theta   = (const float*)d_in[1];
    const float* sigma   = (const float*)d_in[2];
    const float* gamma   = (const float*)d_in[3];
    const float* lambd   = (const float*)d_in[4];
    const float* psi     = (const float*)d_in[5];
    const float* conv2_w = (const float*)d_in[6];
    const float* conv2_b = (const float*)d_in[7];
    const float* fc1_w   = (const float*)d_in[8];
    const float* fc1_b   = (const float*)d_in[9];
    const float* fc2_w   = (const float*)d_in[10];
    const float* fc2_b   = (const float*)d_in[11];
    float* out = (float*)d_out;

    // ws (26.53 MB, under the 27.07 proven-safe watermark):
    //   a2  bf16 K-tiled [98][4096][32] : 0          (25,690,112 B)
    //   w1h f16 [32][16]                : 25,690,112 (1,024 B)
    //   w2h f16 [9][64][32]             : 25,691,136 (36,864 B)
    //   wbf bf16 K-tiled [98][128][32]  : 25,728,000 (802,816 B)
    char* ws = (char*)d_ws;
    u16* a2 = (u16*)ws;
    _Float16* w1h = (_Float16*)(ws + 25690112ull);
    _Float16* w2h = (_Float16*)(ws + 25691136ull);
    u16* wbf = (u16*)(ws + 25728000ull);

    prep_kernel<<<466, 256, 0, stream>>>(theta, sigma, gamma, lambd, psi,
                                         conv2_w, fc1_w, w1h, w2h, wbf);
    fused_conv_kernel<<<BATCH / 2, 256, 0, stream>>>(x, w1h, w2h, conv2_b,
                                                     a2);
    fc_kernel<<<BATCH / 16, 1024, 0, stream>>>(a2, wbf, fc1_b, fc2_w, fc2_b,
                                               out);
}